// Round 1
// baseline (3903.133 us; speedup 1.0000x reference)
//
#include <hip/hip_runtime.h>
#include <cstdint>

#define Dd 768
#define Ff 16384
#define Bb 4096
#define Kk 64

// ---------------- encode + fused top-k ----------------
// 512 blocks x 256 threads; 8 rows/block; 2 features/thread per iter (NT=512)
#define MT  8
#define NTH 256
#define NT  512

__global__ __launch_bounds__(NTH) void sae_enc_topk(
    const float* __restrict__ x, const float* __restrict__ Wenc,
    const float* __restrict__ benc, const float* __restrict__ bdec,
    float* __restrict__ ovals, int* __restrict__ oidx)
{
    __shared__ __align__(16) float xs[MT][Dd];
    __shared__ float cand[MT][NT];

    const int tid  = threadIdx.x;
    const int lane = tid & 63;
    const int wid  = tid >> 6;           // 4 waves; each owns MT/4 = 2 rows
    const int r0   = blockIdx.x * MT;

    // stage x - b_dec (coalesced; xs layout == global layout chunk)
    for (int i = tid; i < MT * Dd; i += NTH)
        xs[i / Dd][i % Dd] = x[(size_t)r0 * Dd + i] - bdec[i % Dd];
    __syncthreads();

    // register-distributed top-64 heap: one slot per lane, per owned row.
    // wmin/wpos are wave-uniform (every lane computes identical reduction).
    float heapv[MT / 4];  int heapi[MT / 4];
    float wmin [MT / 4];  int wpos [MT / 4];
    #pragma unroll
    for (int rr = 0; rr < MT / 4; ++rr) {
        heapv[rr] = -3.4e38f; heapi[rr] = 0; wmin[rr] = -3.4e38f; wpos[rr] = 0;
    }

    for (int f0 = 0; f0 < Ff; f0 += NT) {
        // ---- compute pre-activations for NT features x MT rows ----
        const int fA = f0 + 2 * tid;     // this thread's 2 features: fA, fA+1
        float accA[MT], accB[MT];
        const float bA = benc[fA], bB = benc[fA + 1];
        #pragma unroll
        for (int r = 0; r < MT; ++r) { accA[r] = bA; accB[r] = bB; }

        const float4* wA = (const float4*)(Wenc + (size_t)fA * Dd);
        const float4* wB = (const float4*)(Wenc + (size_t)(fA + 1) * Dd);
        #pragma unroll 2
        for (int d4 = 0; d4 < Dd / 4; ++d4) {
            const float4 a = wA[d4];
            const float4 b = wB[d4];
            #pragma unroll
            for (int r = 0; r < MT; ++r) {
                const float4 xv = *(const float4*)&xs[r][4 * d4]; // broadcast b128
                accA[r] = fmaf(a.x, xv.x, accA[r]);
                accA[r] = fmaf(a.y, xv.y, accA[r]);
                accA[r] = fmaf(a.z, xv.z, accA[r]);
                accA[r] = fmaf(a.w, xv.w, accA[r]);
                accB[r] = fmaf(b.x, xv.x, accB[r]);
                accB[r] = fmaf(b.y, xv.y, accB[r]);
                accB[r] = fmaf(b.z, xv.z, accB[r]);
                accB[r] = fmaf(b.w, xv.w, accB[r]);
            }
        }
        #pragma unroll
        for (int r = 0; r < MT; ++r) {
            cand[r][2 * tid]     = accA[r];
            cand[r][2 * tid + 1] = accB[r];
        }
        __syncthreads();

        // ---- merge candidates into per-row top-64 (wave-parallel) ----
        #pragma unroll
        for (int rr = 0; rr < MT / 4; ++rr) {
            const int r = wid * (MT / 4) + rr;
            for (int base = 0; base < NT; base += 64) {
                const float v  = cand[r][base + lane];
                const int   fi = f0 + base + lane;
                unsigned long long mask = __ballot(v > wmin[rr]);
                while (mask) {
                    const int   s  = __ffsll(mask) - 1;
                    const float vs = __shfl(v,  s);
                    const int   fs = __shfl(fi, s);
                    if (lane == wpos[rr]) { heapv[rr] = vs; heapi[rr] = fs; }
                    // recompute min+argmin over 64 slots (strict total order
                    // via position tie-break so all lanes agree)
                    float hv = heapv[rr]; int hp = lane;
                    #pragma unroll
                    for (int off = 32; off > 0; off >>= 1) {
                        const float ov = __shfl_xor(hv, off);
                        const int   op = __shfl_xor(hp, off);
                        if (ov < hv || (ov == hv && op < hp)) { hv = ov; hp = op; }
                    }
                    wmin[rr] = hv; wpos[rr] = hp;
                    mask &= (mask - 1);
                    mask &= __ballot(v > hv);
                }
            }
        }
        __syncthreads();
    }

    // write results (slot order arbitrary; scatter/decode is order-independent)
    #pragma unroll
    for (int rr = 0; rr < MT / 4; ++rr) {
        const int r = wid * (MT / 4) + rr;
        ovals[(size_t)(r0 + r) * Kk + lane] = heapv[rr];
        oidx [(size_t)(r0 + r) * Kk + lane] = heapi[rr];
    }
}

// ---------------- W_dec transpose: [D][F] -> [F][D] ----------------
__global__ __launch_bounds__(256) void sae_transpose(
    const float* __restrict__ Wd, float* __restrict__ WdT)
{
    __shared__ float tile[32][33];
    const int f0 = blockIdx.x * 32;
    const int d0 = blockIdx.y * 32;
    const int tx = threadIdx.x, ty = threadIdx.y;
    #pragma unroll
    for (int k = 0; k < 4; ++k)
        tile[ty + 8 * k][tx] = Wd[(size_t)(d0 + ty + 8 * k) * Ff + f0 + tx];
    __syncthreads();
    #pragma unroll
    for (int k = 0; k < 4; ++k)
        WdT[(size_t)(f0 + ty + 8 * k) * Dd + d0 + tx] = tile[tx][ty + 8 * k];
}

// ---------------- sparse decode ----------------
__global__ __launch_bounds__(256) void sae_decode(
    const float* __restrict__ WdT, const float* __restrict__ vals,
    const int* __restrict__ idx, const float* __restrict__ bdec,
    float* __restrict__ out)
{
    __shared__ float sv[Kk];
    __shared__ int   si[Kk];
    const int b = blockIdx.x, tid = threadIdx.x;
    if (tid < Kk) { sv[tid] = vals[(size_t)b * Kk + tid]; si[tid] = idx[(size_t)b * Kk + tid]; }
    __syncthreads();
    float a0 = bdec[tid], a1 = bdec[tid + 256], a2 = bdec[tid + 512];
    for (int k = 0; k < Kk; ++k) {
        const float v = sv[k];
        const float* row = WdT + (size_t)si[k] * Dd;
        a0 = fmaf(v, row[tid],       a0);
        a1 = fmaf(v, row[tid + 256], a1);
        a2 = fmaf(v, row[tid + 512], a2);
    }
    out[(size_t)b * Dd + tid]       = a0;
    out[(size_t)b * Dd + tid + 256] = a1;
    out[(size_t)b * Dd + tid + 512] = a2;
}

extern "C" void kernel_launch(void* const* d_in, const int* in_sizes, int n_in,
                              void* d_out, int out_size, void* d_ws, size_t ws_size,
                              hipStream_t stream) {
    const float* x    = (const float*)d_in[0];
    const float* Wenc = (const float*)d_in[1];
    const float* benc = (const float*)d_in[2];
    const float* Wdec = (const float*)d_in[3];
    const float* bdec = (const float*)d_in[4];
    float* out = (float*)d_out;

    char* ws = (char*)d_ws;
    float* WdT  = (float*)ws;                                    // 50,331,648 B
    float* vals = (float*)(ws + (size_t)Ff * Dd * 4);            // 1 MiB
    int*   idx  = (int*)  (ws + (size_t)Ff * Dd * 4 + (size_t)Bb * Kk * 4); // 1 MiB

    sae_transpose<<<dim3(Ff / 32, Dd / 32), dim3(32, 8), 0, stream>>>(Wdec, WdT);
    sae_enc_topk<<<Bb / MT, NTH, 0, stream>>>(x, Wenc, benc, bdec, vals, idx);
    sae_decode<<<Bb, 256, 0, stream>>>(WdT, vals, idx, bdec, out);
}

// Round 3
// 1895.910 us; speedup vs baseline: 2.0587x; 2.0587x over previous
//
#include <hip/hip_runtime.h>
#include <cstdint>
#include <cstddef>

#define Dd 768
#define Ff 16384
#define Bb 4096
#define Kk 64
#define KP 2304           // packed K = 3*768 (hi|lo|hi vs hi|hi|lo)
#define FCH 4096          // feature chunk
#define NCH 4
#define NCAND 128         // screened candidates per row
#define DELTA 1e-3f       // rescore margin (>> screen error ~1e-5)

typedef __bf16 bf16x8 __attribute__((ext_vector_type(8)));
typedef float  f32x4  __attribute__((ext_vector_type(4)));

__device__ __forceinline__ unsigned short f2bf(float f) {
    union { float f; unsigned u; } a; a.f = f;
    unsigned r = a.u + 0x7fffu + ((a.u >> 16) & 1u);   // RNE
    return (unsigned short)(r >> 16);
}
__device__ __forceinline__ float bf2f(unsigned short h) {
    union { float f; unsigned u; } a; a.u = ((unsigned)h) << 16;
    return a.f;
}

#define GLDS16(g, l) __builtin_amdgcn_global_load_lds( \
    (const __attribute__((address_space(1))) void*)(g), \
    (__attribute__((address_space(3))) void*)(l), 16, 0, 0)

// ---------------- pack x - b_dec into bf16 split [hi | lo | hi] ----------------
__global__ __launch_bounds__(256) void conv_x(
    const float* __restrict__ x, const float* __restrict__ bdec,
    unsigned short* __restrict__ Xp)
{
    const int i = blockIdx.x * 256 + threadIdx.x;        // over Bb*Dd
    const int row = i / Dd, col = i - row * Dd;
    const float t = x[i] - bdec[col];
    const unsigned short h = f2bf(t);
    const unsigned short l = f2bf(t - bf2f(h));
    const size_t o = (size_t)row * KP + col;
    Xp[o] = h; Xp[o + Dd] = l; Xp[o + 2 * Dd] = h;
}

// ---------------- pack W_enc into bf16 split [hi | hi | lo] ----------------
__global__ __launch_bounds__(256) void conv_w(
    const float* __restrict__ Wenc, unsigned short* __restrict__ Wp)
{
    const int i = blockIdx.x * 256 + threadIdx.x;        // over Ff*Dd
    const int row = i / Dd, col = i - row * Dd;
    const float t = Wenc[i];
    const unsigned short h = f2bf(t);
    const unsigned short l = f2bf(t - bf2f(h));
    const size_t o = (size_t)row * KP + col;
    Wp[o] = h; Wp[o + Dd] = h; Wp[o + 2 * Dd] = l;
}

// ---------------- bf16 screen GEMM (m97 structure) ----------------
__global__ __launch_bounds__(256) void sae_gemm(
    const unsigned short* __restrict__ Xp,   // [Bb][KP]
    const unsigned short* __restrict__ Wp,   // [Ff][KP]
    const float* __restrict__ benc,
    float* __restrict__ pre,                 // [Bb][FCH] chunk
    int f_base)
{
    __shared__ __align__(16) unsigned short As[128 * 32];
    __shared__ __align__(16) unsigned short Bs[128 * 32];

    const int tid  = threadIdx.x;
    const int lane = tid & 63;
    const int w    = tid >> 6;
    const int wm   = w >> 1, wn = w & 1;     // 2x2 wave grid, 64x64 per wave
    const int m0   = blockIdx.y * 128;
    const int n0   = blockIdx.x * 128;       // chunk-local
    const int nG   = f_base + n0;            // global feature base

    const int e = tid * 8;
    const unsigned short* gA0 = Xp + (size_t)(m0 + (e >> 5)) * KP + (e & 31);
    const unsigned short* gA1 = Xp + (size_t)(m0 + ((e + 2048) >> 5)) * KP + (e & 31);
    const unsigned short* gB0 = Wp + (size_t)(nG + (e >> 5)) * KP + (e & 31);
    const unsigned short* gB1 = Wp + (size_t)(nG + ((e + 2048) >> 5)) * KP + (e & 31);
    unsigned short* lA0 = &As[w * 512];          // wave-uniform base + lane*16B
    unsigned short* lA1 = &As[2048 + w * 512];
    unsigned short* lB0 = &Bs[w * 512];
    unsigned short* lB1 = &Bs[2048 + w * 512];

    f32x4 acc[4][4];
    #pragma unroll
    for (int i = 0; i < 4; ++i)
        #pragma unroll
        for (int j = 0; j < 4; ++j) acc[i][j] = 0;

    const int aro = (wm * 64 + (lane & 15)) * 32 + (lane >> 4) * 8;
    const int bro = (wn * 64 + (lane & 15)) * 32 + (lane >> 4) * 8;

    for (int k0 = 0; k0 < KP; k0 += 32) {
        __syncthreads();
        GLDS16(gA0 + k0, lA0);
        GLDS16(gA1 + k0, lA1);
        GLDS16(gB0 + k0, lB0);
        GLDS16(gB1 + k0, lB1);
        __syncthreads();
        bf16x8 af[4], bfr[4];
        #pragma unroll
        for (int mi = 0; mi < 4; ++mi) af[mi]  = *(const bf16x8*)&As[aro + mi * 512];
        #pragma unroll
        for (int ni = 0; ni < 4; ++ni) bfr[ni] = *(const bf16x8*)&Bs[bro + ni * 512];
        #pragma unroll
        for (int mi = 0; mi < 4; ++mi)
            #pragma unroll
            for (int ni = 0; ni < 4; ++ni)
                acc[mi][ni] = __builtin_amdgcn_mfma_f32_16x16x32_bf16(
                    af[mi], bfr[ni], acc[mi][ni], 0, 0, 0);
    }

    const int cl = lane & 15;
    const int rl = (lane >> 4) * 4;
    #pragma unroll
    for (int ni = 0; ni < 4; ++ni) {
        const int ccol = n0 + wn * 64 + ni * 16 + cl;
        const float bia = benc[f_base + ccol];
        #pragma unroll
        for (int mi = 0; mi < 4; ++mi) {
            const int row = m0 + wm * 64 + mi * 16 + rl;
            #pragma unroll
            for (int j = 0; j < 4; ++j)
                pre[(size_t)(row + j) * FCH + ccol] = acc[mi][ni][j] + bia;
        }
    }
}

// ---------------- streaming top-128 over a feature chunk ----------------
// 2 heap slots per lane; pos = slot*64 + lane; wave-uniform min/argmin.
__device__ __forceinline__ void minpos2(float h0, float h1, int lane,
                                        float& mv_o, int& mp_o) {
    float mv; int mp;
    if (h1 < h0) { mv = h1; mp = lane + 64; } else { mv = h0; mp = lane; }
    #pragma unroll
    for (int off = 32; off > 0; off >>= 1) {
        const float ov = __shfl_xor(mv, off);
        const int   op = __shfl_xor(mp, off);
        if (ov < mv || (ov == mv && op < mp)) { mv = ov; mp = op; }
    }
    mv_o = mv; mp_o = mp;
}

__global__ __launch_bounds__(256) void sae_topk(
    const float* __restrict__ pre,           // [Bb][FCH]
    float* __restrict__ v128, int* __restrict__ i128,
    int f_base, int first)
{
    const int tid = threadIdx.x, lane = tid & 63, w = tid >> 6;
    const int rbase = blockIdx.x * 8 + w * 2;
    for (int rr = 0; rr < 2; ++rr) {
        const int r = rbase + rr;
        float hv0, hv1; int hi0, hi1;
        if (first) { hv0 = hv1 = -3.4e38f; hi0 = hi1 = 0; }
        else {
            hv0 = v128[(size_t)r * NCAND + lane];
            hv1 = v128[(size_t)r * NCAND + 64 + lane];
            hi0 = i128[(size_t)r * NCAND + lane];
            hi1 = i128[(size_t)r * NCAND + 64 + lane];
        }
        float wmin; int wpos;
        minpos2(hv0, hv1, lane, wmin, wpos);
        const float4* rowp = (const float4*)(pre + (size_t)r * FCH);
        for (int j = 0; j < FCH / 256; ++j) {
            const float4 v4 = rowp[j * 64 + lane];
            #pragma unroll
            for (int c = 0; c < 4; ++c) {
                const float v = (c == 0) ? v4.x : (c == 1) ? v4.y : (c == 2) ? v4.z : v4.w;
                const int fi = f_base + j * 256 + lane * 4 + c;
                unsigned long long mask = __ballot(v > wmin);
                while (mask) {
                    const int   s  = __ffsll(mask) - 1;
                    const float vs = __shfl(v,  s);
                    const int   fs = __shfl(fi, s);
                    if ((wpos & 63) == lane) {
                        if (wpos < 64) { hv0 = vs; hi0 = fs; }
                        else           { hv1 = vs; hi1 = fs; }
                    }
                    minpos2(hv0, hv1, lane, wmin, wpos);
                    mask &= (mask - 1);
                    mask &= __ballot(v > wmin);
                }
            }
        }
        v128[(size_t)r * NCAND + lane]      = hv0;
        v128[(size_t)r * NCAND + 64 + lane] = hv1;
        i128[(size_t)r * NCAND + lane]      = hi0;
        i128[(size_t)r * NCAND + 64 + lane] = hi1;
    }
}

// ---------------- exact fp64 rescore + final top-64 ----------------
__global__ __launch_bounds__(256) void sae_rescore(
    const float* __restrict__ x, const float* __restrict__ Wenc,
    const float* __restrict__ benc, const float* __restrict__ bdec,
    const float* __restrict__ v128, const int* __restrict__ i128,
    float* __restrict__ ovals, int* __restrict__ oidx)
{
    __shared__ float  xr[Dd];
    __shared__ float  cv[NCAND];
    __shared__ int    ci[NCAND];
    __shared__ int    act[NCAND];
    __shared__ double es[NCAND];
    __shared__ float  tau;

    const int r = blockIdx.x, tid = threadIdx.x;
    const int lane = tid & 63, w = tid >> 6;

    xr[tid]       = x[(size_t)r * Dd + tid]       - bdec[tid];
    xr[tid + 256] = x[(size_t)r * Dd + tid + 256] - bdec[tid + 256];
    xr[tid + 512] = x[(size_t)r * Dd + tid + 512] - bdec[tid + 512];
    if (tid < NCAND) {
        cv[tid] = v128[(size_t)r * NCAND + tid];
        ci[tid] = i128[(size_t)r * NCAND + tid];
    }
    __syncthreads();

    // rank approx values (strict total order via index tie-break); tau = rank-63 value
    if (tid < NCAND) {
        const float v = cv[tid];
        int rk = 0;
        for (int j = 0; j < NCAND; ++j) {
            const float vj = cv[j];
            rk += (vj > v) || (vj == v && j < tid);
        }
        if (rk == 63) tau = v;
    }
    __syncthreads();
    if (tid < NCAND) act[tid] = (cv[tid] >= tau - DELTA) ? 1 : 0;
    __syncthreads();

    // fp64 exact dot for active candidates: one wave per candidate
    for (int c = w; c < NCAND; c += 4) {
        if (act[c]) {
            const int f = ci[c];
            const float* wrow = Wenc + (size_t)f * Dd;
            double a = 0.0;
            #pragma unroll
            for (int j = 0; j < Dd / 64; ++j)
                a = fma((double)wrow[j * 64 + lane], (double)xr[j * 64 + lane], a);
            #pragma unroll
            for (int off = 32; off > 0; off >>= 1)
                a += __shfl_xor(a, off);
            if (lane == 0) es[c] = a + (double)benc[f];
        } else {
            if (lane == 0) es[c] = -1.0e300;
        }
    }
    __syncthreads();

    // exact top-64 of rescored set
    if (tid < NCAND) {
        const double e = es[tid];
        int rk = 0;
        for (int j = 0; j < NCAND; ++j) {
            const double ej = es[j];
            rk += (ej > e) || (ej == e && j < tid);
        }
        if (act[tid] && rk < Kk) {
            ovals[(size_t)r * Kk + rk] = (float)e;
            oidx [(size_t)r * Kk + rk] = ci[tid];
        }
    }
}

// ---------------- W_dec transpose: [D][F] -> [F][D] ----------------
__global__ __launch_bounds__(256) void sae_transpose(
    const float* __restrict__ Wd, float* __restrict__ WdT)
{
    __shared__ float tile[32][33];
    const int f0 = blockIdx.x * 32;
    const int d0 = blockIdx.y * 32;
    const int tx = threadIdx.x, ty = threadIdx.y;
    #pragma unroll
    for (int k = 0; k < 4; ++k)
        tile[ty + 8 * k][tx] = Wd[(size_t)(d0 + ty + 8 * k) * Ff + f0 + tx];
    __syncthreads();
    #pragma unroll
    for (int k = 0; k < 4; ++k)
        WdT[(size_t)(f0 + ty + 8 * k) * Dd + d0 + tx] = tile[tx][ty + 8 * k];
}

// ---------------- sparse decode ----------------
__global__ __launch_bounds__(256) void sae_decode(
    const float* __restrict__ WdT, const float* __restrict__ vals,
    const int* __restrict__ idx, const float* __restrict__ bdec,
    float* __restrict__ out)
{
    __shared__ float sv[Kk];
    __shared__ int   si[Kk];
    const int b = blockIdx.x, tid = threadIdx.x;
    if (tid < Kk) { sv[tid] = vals[(size_t)b * Kk + tid]; si[tid] = idx[(size_t)b * Kk + tid]; }
    __syncthreads();
    float a0 = bdec[tid], a1 = bdec[tid + 256], a2 = bdec[tid + 512];
    for (int k = 0; k < Kk; ++k) {
        const float v = sv[k];
        const float* row = WdT + (size_t)si[k] * Dd;
        a0 = fmaf(v, row[tid],       a0);
        a1 = fmaf(v, row[tid + 256], a1);
        a2 = fmaf(v, row[tid + 512], a2);
    }
    out[(size_t)b * Dd + tid]       = a0;
    out[(size_t)b * Dd + tid + 256] = a1;
    out[(size_t)b * Dd + tid + 512] = a2;
}

extern "C" void kernel_launch(void* const* d_in, const int* in_sizes, int n_in,
                              void* d_out, int out_size, void* d_ws, size_t ws_size,
                              hipStream_t stream) {
    const float* x    = (const float*)d_in[0];
    const float* Wenc = (const float*)d_in[1];
    const float* benc = (const float*)d_in[2];
    const float* Wdec = (const float*)d_in[3];
    const float* bdec = (const float*)d_in[4];
    float* out = (float*)d_out;

    char* ws = (char*)d_ws;
    size_t o = 0;
    float*          WdT  = (float*)(ws + o);          o += (size_t)Ff * Dd * 4;     // 50.3 MB
    unsigned short* Xp   = (unsigned short*)(ws + o); o += (size_t)Bb * KP * 2;     // 18.9 MB
    unsigned short* Wp   = (unsigned short*)(ws + o); o += (size_t)Ff * KP * 2;     // 75.5 MB
    float*          pre  = (float*)(ws + o);          o += (size_t)Bb * FCH * 4;    // 67.1 MB
    float*          v128 = (float*)(ws + o);          o += (size_t)Bb * NCAND * 4;  // 2.1 MB
    int*            i128 = (int*)(ws + o);            o += (size_t)Bb * NCAND * 4;  // 2.1 MB
    float*          vals = (float*)(ws + o);          o += (size_t)Bb * Kk * 4;     // 1.0 MB
    int*            idxb = (int*)(ws + o);                                          // 1.0 MB

    sae_transpose<<<dim3(Ff / 32, Dd / 32), dim3(32, 8), 0, stream>>>(Wdec, WdT);
    conv_x<<<(Bb * Dd) / 256, 256, 0, stream>>>(x, bdec, Xp);
    conv_w<<<(Ff * Dd) / 256, 256, 0, stream>>>(Wenc, Wp);
    for (int c = 0; c < NCH; ++c) {
        sae_gemm<<<dim3(FCH / 128, Bb / 128), 256, 0, stream>>>(Xp, Wp, benc, pre, c * FCH);
        sae_topk<<<Bb / 8, 256, 0, stream>>>(pre, v128, i128, c * FCH, c == 0);
    }
    sae_rescore<<<Bb, 256, 0, stream>>>(x, Wenc, benc, bdec, v128, i128, vals, idxb);
    sae_decode<<<Bb, 256, 0, stream>>>(WdT, vals, idxb, bdec, out);
}

// Round 4
// 767.960 us; speedup vs baseline: 5.0825x; 2.4688x over previous
//
#include <hip/hip_runtime.h>
#include <cstdint>
#include <cstddef>

#define Dd 768
#define Ff 16384
#define Bb 4096
#define Kk 64
#define MCH 1024          // rows per chunk
#define NCHR 4            // chunks (Bb / MCH)
#define NCAND 128         // candidate cap per row (expected ~72)
#define BINS 512          // histogram bins over [0,4), width 1/128
#define MARGIN 0.015f     // >> bf16 screen error tail (~5e-3)

typedef __bf16 bf16x8 __attribute__((ext_vector_type(8)));
typedef float  f32x4  __attribute__((ext_vector_type(4)));

__device__ __forceinline__ unsigned short f2bf(float f) {
    union { float f; unsigned u; } a; a.f = f;
    unsigned r = a.u + 0x7fffu + ((a.u >> 16) & 1u);   // RNE
    return (unsigned short)(r >> 16);
}

#define GLDS16(g, l) __builtin_amdgcn_global_load_lds( \
    (const __attribute__((address_space(1))) void*)(g), \
    (__attribute__((address_space(3))) void*)(l), 16, 0, 0)

// ---------------- pack x - b_dec into bf16 ----------------
__global__ __launch_bounds__(256) void conv_x(
    const float* __restrict__ x, const float* __restrict__ bdec,
    unsigned short* __restrict__ Xb)
{
    const int i = blockIdx.x * 256 + threadIdx.x;        // over Bb*Dd
    const int col = i % Dd;
    Xb[i] = f2bf(x[i] - bdec[col]);
}

// ---------------- pack W_enc into bf16 ----------------
__global__ __launch_bounds__(256) void conv_w(
    const float* __restrict__ Wenc, unsigned short* __restrict__ Wb)
{
    const int i = blockIdx.x * 256 + threadIdx.x;        // over Ff*Dd
    Wb[i] = f2bf(Wenc[i]);
}

// ---------------- bf16 screen GEMM (m97 structure), K=768 ----------------
// pre[m][n] (chunk-local m) = Xb[m_base+m,:]·Wb[n,:] + benc[n]
__global__ __launch_bounds__(256) void sae_gemm(
    const unsigned short* __restrict__ Xb,   // [Bb][Dd]
    const unsigned short* __restrict__ Wb,   // [Ff][Dd]
    const float* __restrict__ benc,
    float* __restrict__ pre,                 // [MCH][Ff]
    int m_base)
{
    __shared__ __align__(16) unsigned short As[128 * 32];
    __shared__ __align__(16) unsigned short Bs[128 * 32];

    const int tid  = threadIdx.x;
    const int lane = tid & 63;
    const int w    = tid >> 6;
    const int wm   = w >> 1, wn = w & 1;     // 2x2 wave grid, 64x64 per wave
    const int m0   = blockIdx.y * 128;       // chunk-local row base
    const int n0   = blockIdx.x * 128;       // global feature base
    const int gm0  = m_base + m0;

    const int e = tid * 8;                   // LDS elem offset; row=e/32, k=e%32
    const unsigned short* gA0 = Xb + (size_t)(gm0 + (e >> 5)) * Dd + (e & 31);
    const unsigned short* gA1 = Xb + (size_t)(gm0 + 64 + (e >> 5)) * Dd + (e & 31);
    const unsigned short* gB0 = Wb + (size_t)(n0 + (e >> 5)) * Dd + (e & 31);
    const unsigned short* gB1 = Wb + (size_t)(n0 + 64 + (e >> 5)) * Dd + (e & 31);
    unsigned short* lA0 = &As[w * 512];      // wave-uniform base + lane*16B
    unsigned short* lA1 = &As[2048 + w * 512];
    unsigned short* lB0 = &Bs[w * 512];
    unsigned short* lB1 = &Bs[2048 + w * 512];

    f32x4 acc[4][4];
    #pragma unroll
    for (int i = 0; i < 4; ++i)
        #pragma unroll
        for (int j = 0; j < 4; ++j) acc[i][j] = 0;

    const int aro = (wm * 64 + (lane & 15)) * 32 + (lane >> 4) * 8;
    const int bro = (wn * 64 + (lane & 15)) * 32 + (lane >> 4) * 8;

    for (int k0 = 0; k0 < Dd; k0 += 32) {    // 24 K-iters
        __syncthreads();
        GLDS16(gA0 + k0, lA0);
        GLDS16(gA1 + k0, lA1);
        GLDS16(gB0 + k0, lB0);
        GLDS16(gB1 + k0, lB1);
        __syncthreads();
        bf16x8 af[4], bfr[4];
        #pragma unroll
        for (int mi = 0; mi < 4; ++mi) af[mi]  = *(const bf16x8*)&As[aro + mi * 512];
        #pragma unroll
        for (int ni = 0; ni < 4; ++ni) bfr[ni] = *(const bf16x8*)&Bs[bro + ni * 512];
        #pragma unroll
        for (int mi = 0; mi < 4; ++mi)
            #pragma unroll
            for (int ni = 0; ni < 4; ++ni)
                acc[mi][ni] = __builtin_amdgcn_mfma_f32_16x16x32_bf16(
                    af[mi], bfr[ni], acc[mi][ni], 0, 0, 0);
    }

    // epilogue: C row = (lane>>4)*4 + j, col = lane&15 ; fuse +benc
    const int cl = lane & 15;
    const int rl = (lane >> 4) * 4;
    #pragma unroll
    for (int ni = 0; ni < 4; ++ni) {
        const int ccol = n0 + wn * 64 + ni * 16 + cl;
        const float bia = benc[ccol];
        #pragma unroll
        for (int mi = 0; mi < 4; ++mi) {
            const int row = m0 + wm * 64 + mi * 16 + rl;   // chunk-local
            #pragma unroll
            for (int j = 0; j < 4; ++j)
                pre[(size_t)(row + j) * Ff + ccol] = acc[mi][ni][j] + bia;
        }
    }
}

// ---------------- histogram select: per-row tau + compaction ----------------
// 2 rows/block, 128 threads/row. Pass 1: LDS histogram. Pass 2: serial suffix
// scan -> tau (rank-64 bin edge). Pass 3: compact indices with v >= tau-MARGIN.
__global__ __launch_bounds__(256) void sae_select(
    const float* __restrict__ pre,           // [MCH][Ff]
    int* __restrict__ ci, int* __restrict__ ccount,
    int m_base)
{
    __shared__ unsigned hist[2][BINS];
    __shared__ float tauS[2];
    __shared__ int lcnt[2];

    const int tid = threadIdx.x;
    const int r   = tid >> 7;                // 0..1
    const int l   = tid & 127;
    const int rloc = blockIdx.x * 2 + r;     // chunk-local row
    const int rg   = m_base + rloc;          // global row

    for (int i = tid; i < 2 * BINS; i += 256) ((unsigned*)hist)[i] = 0;
    if (tid < 2) lcnt[tid] = 0;
    __syncthreads();

    const float4* rp = (const float4*)(pre + (size_t)rloc * Ff);
    for (int j = 0; j < 32; ++j) {
        const float4 v4 = rp[j * 128 + l];
        #pragma unroll
        for (int c = 0; c < 4; ++c) {
            const float v = (c == 0) ? v4.x : (c == 1) ? v4.y : (c == 2) ? v4.z : v4.w;
            if (v >= 0.0f) {
                const int b = min((int)(v * 128.0f), BINS - 1);
                atomicAdd(&hist[r][b], 1u);
            }
        }
    }
    __syncthreads();

    if (l == 0) {                            // threads 0 and 128
        unsigned acc = 0; float tv = -1.0e30f;
        for (int j = BINS - 1; j >= 0; --j) {
            acc += hist[r][j];
            if (acc >= (unsigned)Kk) { tv = (float)j * 0.0078125f; break; }
        }
        tauS[r] = tv;
    }
    __syncthreads();

    const float thr = tauS[r] - MARGIN;
    for (int j = 0; j < 32; ++j) {
        const float4 v4 = rp[j * 128 + l];
        #pragma unroll
        for (int c = 0; c < 4; ++c) {
            const float v = (c == 0) ? v4.x : (c == 1) ? v4.y : (c == 2) ? v4.z : v4.w;
            if (v >= thr) {
                const int p = atomicAdd(&lcnt[r], 1);
                if (p < NCAND) ci[(size_t)rg * NCAND + p] = j * 512 + l * 4 + c;
            }
        }
    }
    __syncthreads();
    if (l == 0) ccount[rg] = min(lcnt[r], NCAND);
}

// ---------------- exact fp64 rescore + final top-64 ----------------
__global__ __launch_bounds__(256) void sae_rescore(
    const float* __restrict__ x, const float* __restrict__ Wenc,
    const float* __restrict__ benc, const float* __restrict__ bdec,
    const int* __restrict__ ci, const int* __restrict__ ccount,
    float* __restrict__ ovals, int* __restrict__ oidx)
{
    __shared__ float  xr[Dd];
    __shared__ int    cis[NCAND];
    __shared__ double es[NCAND];
    __shared__ int    cnt;

    const int r = blockIdx.x, tid = threadIdx.x;
    const int lane = tid & 63, w = tid >> 6;

    xr[tid]       = x[(size_t)r * Dd + tid]       - bdec[tid];
    xr[tid + 256] = x[(size_t)r * Dd + tid + 256] - bdec[tid + 256];
    xr[tid + 512] = x[(size_t)r * Dd + tid + 512] - bdec[tid + 512];
    if (tid == 0) cnt = ccount[r];
    if (tid < NCAND) cis[tid] = ci[(size_t)r * NCAND + tid];
    if (tid < Kk) { ovals[(size_t)r * Kk + tid] = 0.0f; oidx[(size_t)r * Kk + tid] = 0; }
    __syncthreads();

    for (int c = w; c < NCAND; c += 4) {
        double e = -1.0e300;
        if (c < cnt) {
            const int f = cis[c];
            const float* wrow = Wenc + (size_t)f * Dd;
            double a = 0.0;
            #pragma unroll
            for (int j = 0; j < Dd / 64; ++j)
                a = fma((double)wrow[j * 64 + lane], (double)xr[j * 64 + lane], a);
            #pragma unroll
            for (int off = 32; off > 0; off >>= 1)
                a += __shfl_xor(a, off);
            e = a + (double)benc[f];
        }
        if (lane == 0) es[c] = e;
    }
    __syncthreads();

    if (tid < NCAND) {
        const double e = es[tid];
        int rk = 0;
        for (int j = 0; j < NCAND; ++j) {
            const double ej = es[j];
            rk += (ej > e) || (ej == e && j < tid);
        }
        if (tid < cnt && rk < Kk) {
            ovals[(size_t)r * Kk + rk] = (float)e;
            oidx [(size_t)r * Kk + rk] = cis[tid];
        }
    }
}

// ---------------- W_dec transpose: [D][F] -> [F][D] ----------------
__global__ __launch_bounds__(256) void sae_transpose(
    const float* __restrict__ Wd, float* __restrict__ WdT)
{
    __shared__ float tile[32][33];
    const int f0 = blockIdx.x * 32;
    const int d0 = blockIdx.y * 32;
    const int tx = threadIdx.x, ty = threadIdx.y;
    #pragma unroll
    for (int k = 0; k < 4; ++k)
        tile[ty + 8 * k][tx] = Wd[(size_t)(d0 + ty + 8 * k) * Ff + f0 + tx];
    __syncthreads();
    #pragma unroll
    for (int k = 0; k < 4; ++k)
        WdT[(size_t)(f0 + ty + 8 * k) * Dd + d0 + tx] = tile[tx][ty + 8 * k];
}

// ---------------- sparse decode ----------------
__global__ __launch_bounds__(256) void sae_decode(
    const float* __restrict__ WdT, const float* __restrict__ vals,
    const int* __restrict__ idx, const float* __restrict__ bdec,
    float* __restrict__ out)
{
    __shared__ float sv[Kk];
    __shared__ int   si[Kk];
    const int b = blockIdx.x, tid = threadIdx.x;
    if (tid < Kk) { sv[tid] = vals[(size_t)b * Kk + tid]; si[tid] = idx[(size_t)b * Kk + tid]; }
    __syncthreads();
    float a0 = bdec[tid], a1 = bdec[tid + 256], a2 = bdec[tid + 512];
    for (int k = 0; k < Kk; ++k) {
        const float v = sv[k];
        const float* row = WdT + (size_t)si[k] * Dd;
        a0 = fmaf(v, row[tid],       a0);
        a1 = fmaf(v, row[tid + 256], a1);
        a2 = fmaf(v, row[tid + 512], a2);
    }
    out[(size_t)b * Dd + tid]       = a0;
    out[(size_t)b * Dd + tid + 256] = a1;
    out[(size_t)b * Dd + tid + 512] = a2;
}

extern "C" void kernel_launch(void* const* d_in, const int* in_sizes, int n_in,
                              void* d_out, int out_size, void* d_ws, size_t ws_size,
                              hipStream_t stream) {
    const float* x    = (const float*)d_in[0];
    const float* Wenc = (const float*)d_in[1];
    const float* benc = (const float*)d_in[2];
    const float* Wdec = (const float*)d_in[3];
    const float* bdec = (const float*)d_in[4];
    float* out = (float*)d_out;

    char* ws = (char*)d_ws;
    size_t o = 0;
    float*          WdT  = (float*)(ws + o);          o += (size_t)Ff * Dd * 4;     // 50.3 MB
    unsigned short* Xb   = (unsigned short*)(ws + o); o += (size_t)Bb * Dd * 2;     //  6.3 MB
    unsigned short* Wb   = (unsigned short*)(ws + o); o += (size_t)Ff * Dd * 2;     // 25.2 MB
    float*          pre  = (float*)(ws + o);          o += (size_t)MCH * Ff * 4;    // 67.1 MB
    int*            cib  = (int*)(ws + o);            o += (size_t)Bb * NCAND * 4;  //  2.1 MB
    int*            ccnt = (int*)(ws + o);            o += (size_t)Bb * 4;          // 16 KB
    float*          vals = (float*)(ws + o);          o += (size_t)Bb * Kk * 4;     //  1.0 MB
    int*            idxb = (int*)(ws + o);                                          //  1.0 MB

    sae_transpose<<<dim3(Ff / 32, Dd / 32), dim3(32, 8), 0, stream>>>(Wdec, WdT);
    conv_x<<<(Bb * Dd) / 256, 256, 0, stream>>>(x, bdec, Xb);
    conv_w<<<(Ff * Dd) / 256, 256, 0, stream>>>(Wenc, Wb);
    for (int c = 0; c < NCHR; ++c) {
        sae_gemm<<<dim3(Ff / 128, MCH / 128), 256, 0, stream>>>(Xb, Wb, benc, pre, c * MCH);
        sae_select<<<MCH / 2, 256, 0, stream>>>(pre, cib, ccnt, c * MCH);
    }
    sae_rescore<<<Bb, 256, 0, stream>>>(x, Wenc, benc, bdec, cib, ccnt, vals, idxb);
    sae_decode<<<Bb, 256, 0, stream>>>(WdT, vals, idxb, bdec, out);
}

// Round 7
// 709.137 us; speedup vs baseline: 5.5041x; 1.0829x over previous
//
#include <hip/hip_runtime.h>
#include <cstdint>
#include <cstddef>

#define Dd 768
#define Ff 16384
#define Bb 4096
#define Kk 64
#define NCAND 128         // candidate cap per row (expected ~84)
#define BINS 512          // histogram bins over [0,4), width 1/128
#define MARGIN 0.04f      // 2*(screen err + bf16 storage round) + bin width

typedef __bf16 bf16x8 __attribute__((ext_vector_type(8)));
typedef float  f32x4  __attribute__((ext_vector_type(4)));
typedef unsigned short u16x8 __attribute__((ext_vector_type(8)));

__device__ __forceinline__ unsigned short f2bf(float f) {
    union { float f; unsigned u; } a; a.f = f;
    unsigned r = a.u + 0x7fffu + ((a.u >> 16) & 1u);   // RNE
    return (unsigned short)(r >> 16);
}
__device__ __forceinline__ float bf2f(unsigned short h) {
    union { float f; unsigned u; } a; a.u = ((unsigned)h) << 16;
    return a.f;
}

#define GLDS16(g, l) __builtin_amdgcn_global_load_lds( \
    (const __attribute__((address_space(1))) void*)(g), \
    (__attribute__((address_space(3))) void*)(l), 16, 0, 0)

// ---------------- pack x - b_dec into bf16 ----------------
__global__ __launch_bounds__(256) void conv_x(
    const float* __restrict__ x, const float* __restrict__ bdec,
    unsigned short* __restrict__ Xb)
{
    const int i = blockIdx.x * 256 + threadIdx.x;        // over Bb*Dd
    const int col = i % Dd;
    Xb[i] = f2bf(x[i] - bdec[col]);
}

// ---------------- pack W_enc into bf16 ----------------
__global__ __launch_bounds__(256) void conv_w(
    const float* __restrict__ Wenc, unsigned short* __restrict__ Wb)
{
    const int i = blockIdx.x * 256 + threadIdx.x;        // over Ff*Dd
    Wb[i] = f2bf(Wenc[i]);
}

// ---------------- bf16 screen GEMM (m97 structure), K=768, bf16 output ------
__global__ __launch_bounds__(256) void sae_gemm(
    const unsigned short* __restrict__ Xb,   // [Bb][Dd]
    const unsigned short* __restrict__ Wb,   // [Ff][Dd]
    const float* __restrict__ benc,
    unsigned short* __restrict__ pre)        // [Bb][Ff] bf16
{
    __shared__ __align__(16) unsigned short As[128 * 32];
    __shared__ __align__(16) unsigned short Bs[128 * 32];

    const int tid  = threadIdx.x;
    const int lane = tid & 63;
    const int w    = tid >> 6;
    const int wm   = w >> 1, wn = w & 1;     // 2x2 wave grid, 64x64 per wave
    const int m0   = blockIdx.y * 128;       // global row base
    const int n0   = blockIdx.x * 128;       // global feature base

    const int e = tid * 8;                   // LDS elem offset; row=e/32, k=e%32
    const unsigned short* gA0 = Xb + (size_t)(m0 + (e >> 5)) * Dd + (e & 31);
    const unsigned short* gA1 = Xb + (size_t)(m0 + 64 + (e >> 5)) * Dd + (e & 31);
    const unsigned short* gB0 = Wb + (size_t)(n0 + (e >> 5)) * Dd + (e & 31);
    const unsigned short* gB1 = Wb + (size_t)(n0 + 64 + (e >> 5)) * Dd + (e & 31);
    unsigned short* lA0 = &As[w * 512];      // wave-uniform base + lane*16B
    unsigned short* lA1 = &As[2048 + w * 512];
    unsigned short* lB0 = &Bs[w * 512];
    unsigned short* lB1 = &Bs[2048 + w * 512];

    f32x4 acc[4][4];
    #pragma unroll
    for (int i = 0; i < 4; ++i)
        #pragma unroll
        for (int j = 0; j < 4; ++j) acc[i][j] = 0;

    const int aro = (wm * 64 + (lane & 15)) * 32 + (lane >> 4) * 8;
    const int bro = (wn * 64 + (lane & 15)) * 32 + (lane >> 4) * 8;

    for (int k0 = 0; k0 < Dd; k0 += 32) {    // 24 K-iters
        __syncthreads();
        GLDS16(gA0 + k0, lA0);
        GLDS16(gA1 + k0, lA1);
        GLDS16(gB0 + k0, lB0);
        GLDS16(gB1 + k0, lB1);
        __syncthreads();
        bf16x8 af[4], bfr[4];
        #pragma unroll
        for (int mi = 0; mi < 4; ++mi) af[mi]  = *(const bf16x8*)&As[aro + mi * 512];
        #pragma unroll
        for (int ni = 0; ni < 4; ++ni) bfr[ni] = *(const bf16x8*)&Bs[bro + ni * 512];
        #pragma unroll
        for (int mi = 0; mi < 4; ++mi)
            #pragma unroll
            for (int ni = 0; ni < 4; ++ni)
                acc[mi][ni] = __builtin_amdgcn_mfma_f32_16x16x32_bf16(
                    af[mi], bfr[ni], acc[mi][ni], 0, 0, 0);
    }

    // epilogue: C row = (lane>>4)*4 + j, col = lane&15 ; fuse +benc, cast bf16
    const int cl = lane & 15;
    const int rl = (lane >> 4) * 4;
    #pragma unroll
    for (int ni = 0; ni < 4; ++ni) {
        const int ccol = n0 + wn * 64 + ni * 16 + cl;
        const float bia = benc[ccol];
        #pragma unroll
        for (int mi = 0; mi < 4; ++mi) {
            const int row = m0 + wm * 64 + mi * 16 + rl;
            #pragma unroll
            for (int j = 0; j < 4; ++j)
                pre[(size_t)(row + j) * Ff + ccol] = f2bf(acc[mi][ni][j] + bia);
        }
    }
}

// ---------------- histogram select: per-row tau + compaction ----------------
// 2 rows/block, 128 threads/row, full F per row (bf16 pre).
__global__ __launch_bounds__(256) void sae_select(
    const unsigned short* __restrict__ pre,  // [Bb][Ff] bf16
    int* __restrict__ ci, int* __restrict__ ccount)
{
    __shared__ unsigned hist[2][BINS];
    __shared__ float tauS[2];
    __shared__ int lcnt[2];

    const int tid = threadIdx.x;
    const int r   = tid >> 7;                // 0..1
    const int l   = tid & 127;
    const int rg  = blockIdx.x * 2 + r;      // global row

    for (int i = tid; i < 2 * BINS; i += 256) ((unsigned*)hist)[i] = 0;
    if (tid < 2) lcnt[tid] = 0;
    __syncthreads();

    const u16x8* rp = (const u16x8*)(pre + (size_t)rg * Ff);  // 2048 vecs/row
    for (int j = 0; j < 16; ++j) {
        const u16x8 v8 = rp[j * 128 + l];
        #pragma unroll
        for (int c = 0; c < 8; ++c) {
            const float v = bf2f(v8[c]);
            if (v >= 0.0f) {
                const int b = min((int)(v * 128.0f), BINS - 1);
                atomicAdd(&hist[r][b], 1u);
            }
        }
    }
    __syncthreads();

    if (l == 0) {                            // threads 0 and 128
        unsigned acc = 0; float tv = -1.0e30f;
        for (int j = BINS - 1; j >= 0; --j) {
            acc += hist[r][j];
            if (acc >= (unsigned)Kk) { tv = (float)j * 0.0078125f; break; }
        }
        tauS[r] = tv;
    }
    __syncthreads();

    const float thr = tauS[r] - MARGIN;
    for (int j = 0; j < 16; ++j) {
        const u16x8 v8 = rp[j * 128 + l];
        #pragma unroll
        for (int c = 0; c < 8; ++c) {
            const float v = bf2f(v8[c]);
            if (v >= thr) {
                const int p = atomicAdd(&lcnt[r], 1);
                if (p < NCAND) ci[(size_t)rg * NCAND + p] = j * 1024 + l * 8 + c;
            }
        }
    }
    __syncthreads();
    if (l == 0) ccount[rg] = min(lcnt[r], NCAND);
}

// ---------------- exact fp64 rescore + final top-64 ----------------
// One block/row; each wave processes 2 candidates concurrently (ILP).
__global__ __launch_bounds__(256) void sae_rescore(
    const float* __restrict__ x, const float* __restrict__ Wenc,
    const float* __restrict__ benc, const float* __restrict__ bdec,
    const int* __restrict__ ci, const int* __restrict__ ccount,
    float* __restrict__ ovals, int* __restrict__ oidx)
{
    __shared__ float  xr[Dd];
    __shared__ int    cis[NCAND];
    __shared__ double es[NCAND];
    __shared__ int    cnt;

    const int r = blockIdx.x, tid = threadIdx.x;
    const int lane = tid & 63, w = tid >> 6;

    xr[tid]       = x[(size_t)r * Dd + tid]       - bdec[tid];
    xr[tid + 256] = x[(size_t)r * Dd + tid + 256] - bdec[tid + 256];
    xr[tid + 512] = x[(size_t)r * Dd + tid + 512] - bdec[tid + 512];
    if (tid == 0) cnt = ccount[r];
    if (tid < NCAND) cis[tid] = ci[(size_t)r * NCAND + tid];
    if (tid < Kk) { ovals[(size_t)r * Kk + tid] = 0.0f; oidx[(size_t)r * Kk + tid] = 0; }
    __syncthreads();

    const int nc = cnt;
    for (int c0 = w; c0 < NCAND; c0 += 8) {
        const int cA = c0, cB = c0 + 4;
        const int fA = cis[(cA < nc) ? cA : 0];
        const int fB = cis[(cB < nc) ? cB : 0];
        const float* wrA = Wenc + (size_t)fA * Dd;
        const float* wrB = Wenc + (size_t)fB * Dd;
        double a = 0.0, b = 0.0;
        #pragma unroll
        for (int j = 0; j < Dd / 64; ++j) {
            const float xv = xr[j * 64 + lane];
            a = fma((double)wrA[j * 64 + lane], (double)xv, a);
            b = fma((double)wrB[j * 64 + lane], (double)xv, b);
        }
        #pragma unroll
        for (int off = 32; off > 0; off >>= 1) {
            a += __shfl_xor(a, off);
            b += __shfl_xor(b, off);
        }
        if (lane == 0) {
            es[cA] = (cA < nc) ? a + (double)benc[fA] : -1.0e300;
            if (cB < NCAND) es[cB] = (cB < nc) ? b + (double)benc[fB] : -1.0e300;
        }
    }
    __syncthreads();

    if (tid < NCAND) {
        const double e = es[tid];
        int rk = 0;
        for (int j = 0; j < NCAND; ++j) {
            const double ej = es[j];
            rk += (ej > e) || (ej == e && j < tid);
        }
        if (tid < nc && rk < Kk) {
            ovals[(size_t)r * Kk + rk] = (float)e;
            oidx [(size_t)r * Kk + rk] = cis[tid];
        }
    }
}

// ---------------- W_dec transpose: [D][F] -> [F][D] ----------------
__global__ __launch_bounds__(256) void sae_transpose(
    const float* __restrict__ Wd, float* __restrict__ WdT)
{
    __shared__ float tile[32][33];
    const int f0 = blockIdx.x * 32;
    const int d0 = blockIdx.y * 32;
    const int tx = threadIdx.x, ty = threadIdx.y;
    #pragma unroll
    for (int k = 0; k < 4; ++k)
        tile[ty + 8 * k][tx] = Wd[(size_t)(d0 + ty + 8 * k) * Ff + f0 + tx];
    __syncthreads();
    #pragma unroll
    for (int k = 0; k < 4; ++k)
        WdT[(size_t)(f0 + ty + 8 * k) * Dd + d0 + tx] = tile[tx][ty + 8 * k];
}

// ---------------- sparse decode ----------------
__global__ __launch_bounds__(256) void sae_decode(
    const float* __restrict__ WdT, const float* __restrict__ vals,
    const int* __restrict__ idx, const float* __restrict__ bdec,
    float* __restrict__ out)
{
    __shared__ float sv[Kk];
    __shared__ int   si[Kk];
    const int b = blockIdx.x, tid = threadIdx.x;
    if (tid < Kk) { sv[tid] = vals[(size_t)b * Kk + tid]; si[tid] = idx[(size_t)b * Kk + tid]; }
    __syncthreads();
    float a0 = bdec[tid], a1 = bdec[tid + 256], a2 = bdec[tid + 512];
    for (int k = 0; k < Kk; ++k) {
        const float v = sv[k];
        const float* row = WdT + (size_t)si[k] * Dd;
        a0 = fmaf(v, row[tid],       a0);
        a1 = fmaf(v, row[tid + 256], a1);
        a2 = fmaf(v, row[tid + 512], a2);
    }
    out[(size_t)b * Dd + tid]       = a0;
    out[(size_t)b * Dd + tid + 256] = a1;
    out[(size_t)b * Dd + tid + 512] = a2;
}

extern "C" void kernel_launch(void* const* d_in, const int* in_sizes, int n_in,
                              void* d_out, int out_size, void* d_ws, size_t ws_size,
                              hipStream_t stream) {
    const float* x    = (const float*)d_in[0];
    const float* Wenc = (const float*)d_in[1];
    const float* benc = (const float*)d_in[2];
    const float* Wdec = (const float*)d_in[3];
    const float* bdec = (const float*)d_in[4];
    float* out = (float*)d_out;

    // Workspace: pre (bf16, 134.2 MB) overlays WdT (50.3 MB) — pre is dead
    // before sae_transpose runs (transpose is launched after sae_select).
    char* ws = (char*)d_ws;
    size_t o = 0;
    unsigned short* pre  = (unsigned short*)(ws);     // [Bb][Ff] bf16
    float*          WdT  = (float*)(ws);              // overlays pre
    o += (size_t)Bb * Ff * 2;                                                       // 134.2 MB
    unsigned short* Xb   = (unsigned short*)(ws + o); o += (size_t)Bb * Dd * 2;     //   6.3 MB
    unsigned short* Wb   = (unsigned short*)(ws + o); o += (size_t)Ff * Dd * 2;     //  25.2 MB
    int*            cib  = (int*)(ws + o);            o += (size_t)Bb * NCAND * 4;  //   2.1 MB
    int*            ccnt = (int*)(ws + o);            o += (size_t)Bb * 4;          //  16 KB
    float*          vals = (float*)(ws + o);          o += (size_t)Bb * Kk * 4;     //   1.0 MB
    int*            idxb = (int*)(ws + o);                                          //   1.0 MB

    conv_x<<<(Bb * Dd) / 256, 256, 0, stream>>>(x, bdec, Xb);
    conv_w<<<(Ff * Dd) / 256, 256, 0, stream>>>(Wenc, Wb);
    sae_gemm<<<dim3(Ff / 128, Bb / 128), 256, 0, stream>>>(Xb, Wb, benc, pre);
    sae_select<<<Bb / 2, 256, 0, stream>>>(pre, cib, ccnt);
    sae_rescore<<<Bb, 256, 0, stream>>>(x, Wenc, benc, bdec, cib, ccnt, vals, idxb);
    sae_transpose<<<dim3(Ff / 32, Dd / 32), dim3(32, 8), 0, stream>>>(Wdec, WdT);
    sae_decode<<<Bb, 256, 0, stream>>>(WdT, vals, idxb, bdec, out);
}

// Round 9
// 548.179 us; speedup vs baseline: 7.1202x; 1.2936x over previous
//
#include <hip/hip_runtime.h>
#include <cstdint>
#include <cstddef>

#define Dd 768
#define Ff 16384
#define Bb 4096
#define Kk 64
#define NCAND 128         // candidate cap per row (expected ~84)
#define BINS 512          // histogram bins over [0,4), width 1/128
#define MARGIN 0.04f      // 2*(screen err + bf16 storage round) + bin width

typedef __bf16 bf16x8 __attribute__((ext_vector_type(8)));
typedef float  f32x4  __attribute__((ext_vector_type(4)));
typedef unsigned short u16x8 __attribute__((ext_vector_type(8)));

__device__ __forceinline__ unsigned short f2bf(float f) {
    union { float f; unsigned u; } a; a.f = f;
    unsigned r = a.u + 0x7fffu + ((a.u >> 16) & 1u);   // RNE
    return (unsigned short)(r >> 16);
}
__device__ __forceinline__ float bf2f(unsigned short h) {
    union { float f; unsigned u; } a; a.u = ((unsigned)h) << 16;
    return a.f;
}
__device__ __forceinline__ float f_lo(unsigned u) {    // low bf16 of a u32
    union { float f; unsigned u; } a; a.u = u << 16; return a.f;
}
__device__ __forceinline__ float f_hi(unsigned u) {    // high bf16 of a u32
    union { float f; unsigned u; } a; a.u = u & 0xffff0000u; return a.f;
}

#define GLDS16(g, l) __builtin_amdgcn_global_load_lds( \
    (const __attribute__((address_space(1))) void*)(g), \
    (__attribute__((address_space(3))) void*)(l), 16, 0, 0)

// ---------------- pack x - b_dec into bf16 ----------------
__global__ __launch_bounds__(256) void conv_x(
    const float* __restrict__ x, const float* __restrict__ bdec,
    unsigned short* __restrict__ Xb)
{
    const int i = blockIdx.x * 256 + threadIdx.x;        // over Bb*Dd
    const int col = i % Dd;
    Xb[i] = f2bf(x[i] - bdec[col]);
}

// ---------------- pack W_enc into bf16 ----------------
__global__ __launch_bounds__(256) void conv_w(
    const float* __restrict__ Wenc, unsigned short* __restrict__ Wb)
{
    const int i = blockIdx.x * 256 + threadIdx.x;        // over Ff*Dd
    Wb[i] = f2bf(Wenc[i]);
}

// ---------------- bf16 screen GEMM (m97 structure), K=768, bf16 output ------
__global__ __launch_bounds__(256) void sae_gemm(
    const unsigned short* __restrict__ Xb,   // [Bb][Dd]
    const unsigned short* __restrict__ Wb,   // [Ff][Dd]
    const float* __restrict__ benc,
    unsigned short* __restrict__ pre)        // [Bb][Ff] bf16
{
    __shared__ __align__(16) unsigned short As[128 * 32];
    __shared__ __align__(16) unsigned short Bs[128 * 32];

    const int tid  = threadIdx.x;
    const int lane = tid & 63;
    const int w    = tid >> 6;
    const int wm   = w >> 1, wn = w & 1;     // 2x2 wave grid, 64x64 per wave
    const int m0   = blockIdx.y * 128;       // global row base
    const int n0   = blockIdx.x * 128;       // global feature base

    const int e = tid * 8;                   // LDS elem offset; row=e/32, k=e%32
    const unsigned short* gA0 = Xb + (size_t)(m0 + (e >> 5)) * Dd + (e & 31);
    const unsigned short* gA1 = Xb + (size_t)(m0 + 64 + (e >> 5)) * Dd + (e & 31);
    const unsigned short* gB0 = Wb + (size_t)(n0 + (e >> 5)) * Dd + (e & 31);
    const unsigned short* gB1 = Wb + (size_t)(n0 + 64 + (e >> 5)) * Dd + (e & 31);
    unsigned short* lA0 = &As[w * 512];      // wave-uniform base + lane*16B
    unsigned short* lA1 = &As[2048 + w * 512];
    unsigned short* lB0 = &Bs[w * 512];
    unsigned short* lB1 = &Bs[2048 + w * 512];

    f32x4 acc[4][4];
    #pragma unroll
    for (int i = 0; i < 4; ++i)
        #pragma unroll
        for (int j = 0; j < 4; ++j) acc[i][j] = 0;

    const int aro = (wm * 64 + (lane & 15)) * 32 + (lane >> 4) * 8;
    const int bro = (wn * 64 + (lane & 15)) * 32 + (lane >> 4) * 8;

    for (int k0 = 0; k0 < Dd; k0 += 32) {    // 24 K-iters
        __syncthreads();
        GLDS16(gA0 + k0, lA0);
        GLDS16(gA1 + k0, lA1);
        GLDS16(gB0 + k0, lB0);
        GLDS16(gB1 + k0, lB1);
        __syncthreads();
        bf16x8 af[4], bfr[4];
        #pragma unroll
        for (int mi = 0; mi < 4; ++mi) af[mi]  = *(const bf16x8*)&As[aro + mi * 512];
        #pragma unroll
        for (int ni = 0; ni < 4; ++ni) bfr[ni] = *(const bf16x8*)&Bs[bro + ni * 512];
        #pragma unroll
        for (int mi = 0; mi < 4; ++mi)
            #pragma unroll
            for (int ni = 0; ni < 4; ++ni)
                acc[mi][ni] = __builtin_amdgcn_mfma_f32_16x16x32_bf16(
                    af[mi], bfr[ni], acc[mi][ni], 0, 0, 0);
    }

    // epilogue: C row = (lane>>4)*4 + j, col = lane&15 ; fuse +benc, cast bf16
    const int cl = lane & 15;
    const int rl = (lane >> 4) * 4;
    #pragma unroll
    for (int ni = 0; ni < 4; ++ni) {
        const int ccol = n0 + wn * 64 + ni * 16 + cl;
        const float bia = benc[ccol];
        #pragma unroll
        for (int mi = 0; mi < 4; ++mi) {
            const int row = m0 + wm * 64 + mi * 16 + rl;
            #pragma unroll
            for (int j = 0; j < 4; ++j)
                pre[(size_t)(row + j) * Ff + ccol] = f2bf(acc[mi][ni][j] + bia);
        }
    }
}

// ---------------- histogram select: per-row tau + compaction ----------------
// 2 rows/block, 128 threads/row, full F per row (bf16 pre).
__global__ __launch_bounds__(256) void sae_select(
    const unsigned short* __restrict__ pre,  // [Bb][Ff] bf16
    int* __restrict__ ci, int* __restrict__ ccount)
{
    __shared__ unsigned hist[2][BINS];
    __shared__ float tauS[2];
    __shared__ int lcnt[2];

    const int tid = threadIdx.x;
    const int r   = tid >> 7;                // 0..1
    const int l   = tid & 127;
    const int rg  = blockIdx.x * 2 + r;      // global row

    for (int i = tid; i < 2 * BINS; i += 256) ((unsigned*)hist)[i] = 0;
    if (tid < 2) lcnt[tid] = 0;
    __syncthreads();

    const u16x8* rp = (const u16x8*)(pre + (size_t)rg * Ff);  // 2048 vecs/row
    for (int j = 0; j < 16; ++j) {
        const u16x8 v8 = rp[j * 128 + l];
        #pragma unroll
        for (int c = 0; c < 8; ++c) {
            const float v = bf2f(v8[c]);
            if (v >= 0.0f) {
                const int b = min((int)(v * 128.0f), BINS - 1);
                atomicAdd(&hist[r][b], 1u);
            }
        }
    }
    __syncthreads();

    if (l == 0) {                            // threads 0 and 128
        unsigned acc = 0; float tv = -1.0e30f;
        for (int j = BINS - 1; j >= 0; --j) {
            acc += hist[r][j];
            if (acc >= (unsigned)Kk) { tv = (float)j * 0.0078125f; break; }
        }
        tauS[r] = tv;
    }
    __syncthreads();

    const float thr = tauS[r] - MARGIN;
    for (int j = 0; j < 16; ++j) {
        const u16x8 v8 = rp[j * 128 + l];
        #pragma unroll
        for (int c = 0; c < 8; ++c) {
            const float v = bf2f(v8[c]);
            if (v >= thr) {
                const int p = atomicAdd(&lcnt[r], 1);
                if (p < NCAND) ci[(size_t)rg * NCAND + p] = j * 1024 + l * 8 + c;
            }
        }
    }
    __syncthreads();
    if (l == 0) ccount[rg] = min(lcnt[r], NCAND);
}

// ---------------- exact fp64 rescore + final top-64 (R4-proven form) --------
__global__ __launch_bounds__(256) void sae_rescore(
    const float* __restrict__ x, const float* __restrict__ Wenc,
    const float* __restrict__ benc, const float* __restrict__ bdec,
    const int* __restrict__ ci, const int* __restrict__ ccount,
    float* __restrict__ ovals, int* __restrict__ oidx)
{
    __shared__ float  xr[Dd];
    __shared__ int    cis[NCAND];
    __shared__ double es[NCAND];
    __shared__ int    cnt;

    const int r = blockIdx.x, tid = threadIdx.x;
    const int lane = tid & 63, w = tid >> 6;

    xr[tid]       = x[(size_t)r * Dd + tid]       - bdec[tid];
    xr[tid + 256] = x[(size_t)r * Dd + tid + 256] - bdec[tid + 256];
    xr[tid + 512] = x[(size_t)r * Dd + tid + 512] - bdec[tid + 512];
    if (tid == 0) cnt = ccount[r];
    if (tid < NCAND) cis[tid] = ci[(size_t)r * NCAND + tid];
    if (tid < Kk) { ovals[(size_t)r * Kk + tid] = 0.0f; oidx[(size_t)r * Kk + tid] = 0; }
    __syncthreads();

    for (int c = w; c < NCAND; c += 4) {
        double e = -1.0e300;
        if (c < cnt) {
            const int f = cis[c];
            const float* wrow = Wenc + (size_t)f * Dd;
            double a = 0.0;
            #pragma unroll
            for (int j = 0; j < Dd / 64; ++j)
                a = fma((double)wrow[j * 64 + lane], (double)xr[j * 64 + lane], a);
            #pragma unroll
            for (int off = 32; off > 0; off >>= 1)
                a += __shfl_xor(a, off);
            e = a + (double)benc[f];
        }
        if (lane == 0) es[c] = e;
    }
    __syncthreads();

    if (tid < NCAND) {
        const double e = es[tid];
        int rk = 0;
        for (int j = 0; j < NCAND; ++j) {
            const double ej = es[j];
            rk += (ej > e) || (ej == e && j < tid);
        }
        if (tid < cnt && rk < Kk) {
            ovals[(size_t)r * Kk + rk] = (float)e;
            oidx [(size_t)r * Kk + rk] = cis[tid];
        }
    }
}

// ---------------- W_dec transpose: [D][F] fp32 -> [F][D] bf16 ----------------
__global__ __launch_bounds__(256) void sae_transpose(
    const float* __restrict__ Wd, unsigned short* __restrict__ WdT)
{
    __shared__ float tile[32][33];
    const int f0 = blockIdx.x * 32;
    const int d0 = blockIdx.y * 32;
    const int tx = threadIdx.x, ty = threadIdx.y;
    #pragma unroll
    for (int k = 0; k < 4; ++k)
        tile[ty + 8 * k][tx] = Wd[(size_t)(d0 + ty + 8 * k) * Ff + f0 + tx];
    __syncthreads();
    #pragma unroll
    for (int k = 0; k < 4; ++k)
        WdT[(size_t)(f0 + ty + 8 * k) * Dd + d0 + tx] = f2bf(tile[tx][ty + 8 * k]);
}

// ---------------- sparse decode (bf16 WdT, LLC-resident) ----------------
// 192 threads: thread t covers d in [4t, 4t+4), reads uint2 (4 bf16) per k.
__global__ __launch_bounds__(192) void sae_decode(
    const unsigned short* __restrict__ WdT, const float* __restrict__ vals,
    const int* __restrict__ idx, const float* __restrict__ bdec,
    float* __restrict__ out)
{
    __shared__ float sv[Kk];
    __shared__ int   si[Kk];
    const int b = blockIdx.x, tid = threadIdx.x;
    if (tid < Kk) { sv[tid] = vals[(size_t)b * Kk + tid]; si[tid] = idx[(size_t)b * Kk + tid]; }
    __syncthreads();
    const int d0 = tid * 4;
    float a0 = bdec[d0], a1 = bdec[d0 + 1], a2 = bdec[d0 + 2], a3 = bdec[d0 + 3];
    for (int k = 0; k < Kk; ++k) {
        const float v = sv[k];
        const uint2 p = *(const uint2*)(WdT + (size_t)si[k] * Dd + d0);
        a0 = fmaf(v, f_lo(p.x), a0);
        a1 = fmaf(v, f_hi(p.x), a1);
        a2 = fmaf(v, f_lo(p.y), a2);
        a3 = fmaf(v, f_hi(p.y), a3);
    }
    float4 o4 = make_float4(a0, a1, a2, a3);
    *(float4*)(out + (size_t)b * Dd + d0) = o4;
}

extern "C" void kernel_launch(void* const* d_in, const int* in_sizes, int n_in,
                              void* d_out, int out_size, void* d_ws, size_t ws_size,
                              hipStream_t stream) {
    const float* x    = (const float*)d_in[0];
    const float* Wenc = (const float*)d_in[1];
    const float* benc = (const float*)d_in[2];
    const float* Wdec = (const float*)d_in[3];
    const float* bdec = (const float*)d_in[4];
    float* out = (float*)d_out;

    char* ws = (char*)d_ws;
    size_t o = 0;
    unsigned short* pre  = (unsigned short*)(ws + o); o += (size_t)Bb * Ff * 2;     // 134.2 MB
    unsigned short* Xb   = (unsigned short*)(ws + o); o += (size_t)Bb * Dd * 2;     //   6.3 MB
    unsigned short* Wb   = (unsigned short*)(ws + o); o += (size_t)Ff * Dd * 2;     //  25.2 MB
    unsigned short* WdT  = (unsigned short*)(ws + o); o += (size_t)Ff * Dd * 2;     //  25.2 MB
    int*            cib  = (int*)(ws + o);            o += (size_t)Bb * NCAND * 4;  //   2.1 MB
    int*            ccnt = (int*)(ws + o);            o += (size_t)Bb * 4;          //  16 KB
    float*          vals = (float*)(ws + o);          o += (size_t)Bb * Kk * 4;     //   1.0 MB
    int*            idxb = (int*)(ws + o);                                          //   1.0 MB

    conv_x<<<(Bb * Dd) / 256, 256, 0, stream>>>(x, bdec, Xb);
    conv_w<<<(Ff * Dd) / 256, 256, 0, stream>>>(Wenc, Wb);
    sae_gemm<<<dim3(Ff / 128, Bb / 128), 256, 0, stream>>>(Xb, Wb, benc, pre);
    sae_select<<<Bb / 2, 256, 0, stream>>>(pre, cib, ccnt);
    sae_rescore<<<Bb, 256, 0, stream>>>(x, Wenc, benc, bdec, cib, ccnt, vals, idxb);
    sae_transpose<<<dim3(Ff / 32, Dd / 32), dim3(32, 8), 0, stream>>>(Wdec, WdT);
    sae_decode<<<Bb, 192, 0, stream>>>(WdT, vals, idxb, bdec, out);
}